// Round 5
// baseline (73.901 us; speedup 1.0000x reference)
//
#include <hip/hip_runtime.h>

#define NSIDE 256
#define HW    65536   // 256*256
#define NB    4       // batch
#define NMAP  8       // 4 pred + 4 gt

// ws layout
// d1p: u32 [NMAP][NSIDE(x)][NSIDE(y)] — packed row-DT, lo16 = fg-sense, hi16 = bg-sense,
//      transposed (x-major) so pass-2 reads columns coalesced. 0xFFFF == 1e9 sentinel.
static const size_t D1_OFF    = 0;
static const size_t ROWFG_OFF = (size_t)NMAP * HW * 4;            // u8 [NMAP][NSIDE]
static const size_t PART_OFF  = ROWFG_OFF + (size_t)NMAP * NSIDE; // f32 [NMAP][NSIDE]

// nearest set bit distance in a 256-bit bitset; returns big value if none
__device__ __forceinline__ int nearest_bit(const unsigned long long* z, int x) {
    int xw = x >> 6, xb = x & 63;
    int best = 1 << 20;
    unsigned long long w = z[xw] & ((2ull << xb) - 1ull);   // bits 0..xb
    if (w) {
        best = x - ((xw << 6) + 63 - __clzll(w));
    } else {
        for (int k = xw - 1; k >= 0; --k) {
            if (z[k]) { best = x - ((k << 6) + 63 - __clzll(z[k])); break; }
        }
    }
    unsigned long long w2 = z[xw] & (~0ull << xb);           // bits xb..63
    if (w2) {
        int r = (xw << 6) + __builtin_ctzll(w2);
        if (r - x < best) best = r - x;
    } else {
        for (int k = xw + 1; k < 4; ++k) {
            if (z[k]) {
                int r = (k << 6) + __builtin_ctzll(z[k]);
                if (r - x < best) best = r - x;
                break;
            }
        }
    }
    return best;
}

// Pass 1: mask + row-DT, register-transposed output.
// grid: NMAP*16 = 128 blocks — block (map m, 16-row group g). 256 threads.
// Rows are loaded coalesced; zero-bitsets built in LDS via ballot; then each
// THREAD owns column x and computes 16 row-DT values, storing them as one
// contiguous 64-byte chunk of the x-major d1p layout (no scattered stores,
// no partial-line write-allocate traffic).
__global__ void k_rowdt(const float* __restrict__ mo, const float* __restrict__ gt,
                        unsigned int* __restrict__ d1p, unsigned char* __restrict__ rowFg) {
    int m = blockIdx.x >> 4;
    int g = blockIdx.x & 15;
    int x = threadIdx.x;
    int y0 = g * 16;
    __shared__ unsigned long long zF[16][4], zB[16][4];

    for (int r = 0; r < 16; ++r) {
        int y = y0 + r;
        int bit;
        if (m < NB) {   // pred: argmax over 2 channels, first-max tie -> 0
            float c0 = mo[(size_t)(m * 2 + 0) * HW + y * NSIDE + x];
            float c1 = mo[(size_t)(m * 2 + 1) * HW + y * NSIDE + x];
            bit = (c1 > c0) ? 1 : 0;
        } else {
            bit = (gt[(size_t)(m - NB) * HW + y * NSIDE + x] > 0.5f) ? 1 : 0;
        }
        unsigned long long balF = __ballot(bit == 0);   // zeros of fg-mask
        unsigned long long balB = __ballot(bit != 0);   // zeros of bg-mask (= fg pixels)
        if ((x & 63) == 0) {
            zF[r][x >> 6] = balF;
            zB[r][x >> 6] = balB;
        }
    }
    __syncthreads();

    unsigned int res[16];
#pragma unroll
    for (int r = 0; r < 16; ++r) {
        int dF = nearest_bit(zF[r], x);   // wave-uniform word index -> LDS broadcast
        int dB = nearest_bit(zB[r], x);
        unsigned int vF = (dF > 255) ? 0xFFFFu : (unsigned int)(dF * dF);
        unsigned int vB = (dB > 255) ? 0xFFFFu : (unsigned int)(dB * dB);
        res[r] = vF | (vB << 16);
    }
    // 64 contiguous bytes per thread at d1p[m][x][y0..y0+15]
    unsigned int* dst = &d1p[((size_t)m * NSIDE + x) * NSIDE + y0];
    uint4* dst4 = (uint4*)dst;
#pragma unroll
    for (int q = 0; q < 4; ++q)
        dst4[q] = make_uint4(res[q * 4 + 0], res[q * 4 + 1], res[q * 4 + 2], res[q * 4 + 3]);
    if (x < 16) {
        int r = x;
        rowFg[m * NSIDE + y0 + r] =
            ((zB[r][0] | zB[r][1] | zB[r][2] | zB[r][3]) != 0ull) ? 1 : 0;
    }
}

// Pass 2 (along H) + err-weighted partial sums, with outward early-exit scan.
// grid: NB*256 blocks (one per (image, column)), 256 threads (one per y).
// Exact: same fp32 min terms as the reference brute force, scanned outward from
// j=y. A plane's min cannot improve once r^2 >= that plane's current best
// (c[j] >= 0), so the wave may stop when r^2 >= MAX over all live planes.
// Lanes with err==0 contribute 0 regardless -> their bests are zeroed so they
// never hold the wave back.
__global__ void k_colreduce(const unsigned int* __restrict__ d1p,
                            float* __restrict__ part) {
    int b = blockIdx.x >> 8;
    int x = blockIdx.x & 255;
    int y = threadIdx.x;
    __shared__ float cPf[NSIDE], cPb[NSIDE], cGf[NSIDE], cGb[NSIDE];
    unsigned int P = d1p[((size_t)b * NSIDE + x) * NSIDE + y];
    unsigned int G = d1p[((size_t)(NB + b) * NSIDE + x) * NSIDE + y];
    unsigned int pf = P & 0xFFFFu, pb = P >> 16;
    unsigned int gf = G & 0xFFFFu, gb = G >> 16;
    cPf[y] = (pf == 0xFFFFu) ? 1e9f : (float)pf;
    cPb[y] = (pb == 0xFFFFu) ? 1e9f : (float)pb;
    cGf[y] = (gf == 0xFFFFu) ? 1e9f : (float)gf;
    cGb[y] = (gb == 0xFFFFu) ? 1e9f : (float)gb;
    __syncthreads();
    // err: fg-sense row-DT is 0 iff pixel is bg -> predBit = (pf != 0)
    float e = ((pf != 0u) != (gf != 0u)) ? 1.0f : 0.0f;
    float bPf = cPf[y], bPb = cPb[y], bGf = cGf[y], bGb = cGb[y];
    if (e == 0.0f) { bPf = 0.0f; bPb = 0.0f; bGf = 0.0f; bGb = 0.0f; }
    float fr = 0.0f;
    for (int r = 1; r < NSIDE; ++r) {
        fr += 1.0f;
        float drr = fr * fr;
        float bmax = fmaxf(fmaxf(bPf, bPb), fmaxf(bGf, bGb));   // MAX: all planes settled
        if (__all(drr >= bmax)) break;
        int jm = y - r, jp = y + r;
        int jmc = jm < 0 ? 0 : jm;
        int jpc = jp > (NSIDE - 1) ? (NSIDE - 1) : jp;
        float aPf = cPf[jmc], aPb = cPb[jmc], aGf = cGf[jmc], aGb = cGb[jmc];
        float qPf = cPf[jpc], qPb = cPb[jpc], qGf = cGf[jpc], qGb = cGb[jpc];
        if (jm < 0) { aPf = 3e9f; aPb = 3e9f; aGf = 3e9f; aGb = 3e9f; }
        if (jp > NSIDE - 1) { qPf = 3e9f; qPb = 3e9f; qGf = 3e9f; qGb = 3e9f; }
        bPf = fminf(bPf, fminf(aPf, qPf) + drr);
        bPb = fminf(bPb, fminf(aPb, qPb) + drr);
        bGf = fminf(bGf, fminf(aGf, qGf) + drr);
        bGb = fminf(bGb, fminf(aGb, qGb) + drr);
    }
    float sP = e * (bPf + bPb);   // pred_dt^2 (one sqEDT is exactly 0 per pixel)
    float sG = e * (bGf + bGb);   // gt_dt^2
#pragma unroll
    for (int off = 32; off > 0; off >>= 1) {
        sP += __shfl_down(sP, off, 64);
        sG += __shfl_down(sG, off, 64);
    }
    __shared__ float rP[4], rG[4];
    int wid = threadIdx.x >> 6;
    if ((threadIdx.x & 63) == 0) { rP[wid] = sP; rG[wid] = sG; }
    __syncthreads();
    if (threadIdx.x == 0) {
        part[b * NSIDE + x]        = rP[0] + rP[1] + rP[2] + rP[3];
        part[(NB + b) * NSIDE + x] = rG[0] + rG[1] + rG[2] + rG[3];
    }
}

// Final: per-map has-fg guard + deterministic sum. 1 block, 256 threads (4 waves).
__global__ void k_final(const unsigned char* __restrict__ rowFg,
                        const float* __restrict__ part,
                        float* __restrict__ out) {
    int tid = threadIdx.x;
    int lane = tid & 63, w = tid >> 6;
    __shared__ int hasFg[NMAP];
    __shared__ float red[NMAP];
    if (tid < NMAP) hasFg[tid] = 0;
    __syncthreads();
    unsigned long long v = ((const unsigned long long*)rowFg)[tid];  // 256 u64 = 2048 B
    if (v) atomicOr(&hasFg[tid >> 5], 1);   // LDS atomic, map = tid>>5
    // each wave reduces two maps via float4 loads
#pragma unroll
    for (int k = 0; k < 2; ++k) {
        int m = 2 * w + k;
        float4 f = ((const float4*)part)[m * 64 + lane];
        float s = f.x + f.y + f.z + f.w;
#pragma unroll
        for (int off = 32; off > 0; off >>= 1) s += __shfl_down(s, off, 64);
        if (lane == 0) red[m] = s;
    }
    __syncthreads();
    if (tid == 0) {
        double t = 0.0;
#pragma unroll
        for (int m = 0; m < NMAP; ++m)
            if (hasFg[m]) t += (double)red[m];
        out[0] = (float)(t * (1.0 / (double)(NB * HW)));
    }
}

extern "C" void kernel_launch(void* const* d_in, const int* in_sizes, int n_in,
                              void* d_out, int out_size, void* d_ws, size_t ws_size,
                              hipStream_t stream) {
    const float* mo = (const float*)d_in[0];
    const float* gt = (const float*)d_in[1];
    float* out = (float*)d_out;
    char* ws = (char*)d_ws;

    unsigned int* d1p    = (unsigned int*)(ws + D1_OFF);
    unsigned char* rowFg = (unsigned char*)(ws + ROWFG_OFF);
    float* part          = (float*)(ws + PART_OFF);

    hipLaunchKernelGGL(k_rowdt,     dim3(NMAP * 16), dim3(256), 0, stream, mo, gt, d1p, rowFg);
    hipLaunchKernelGGL(k_colreduce, dim3(NB * 256),  dim3(256), 0, stream, d1p, part);
    hipLaunchKernelGGL(k_final,     dim3(1),         dim3(256), 0, stream, rowFg, part, out);
}

// Round 6
// 64.619 us; speedup vs baseline: 1.1437x; 1.1437x over previous
//
#include <hip/hip_runtime.h>

#define NSIDE 256
#define HW    65536   // 256*256
#define NB    4       // batch
#define NMAP  8       // 4 pred + 4 gt

typedef unsigned long long u64;

// ws layout
// zz: u64 [NMAP][NSIDE][4] — per-row fg-pixel bitset (bit x set = pixel fg).
//     Both DT senses derive from it (zeros-of-fg = complement).
static const size_t ZZ_OFF    = 0;
static const size_t ROWFG_OFF = (size_t)NMAP * NSIDE * 4 * 8;      // u8 [NMAP][NSIDE] (64 KiB)
static const size_t PART_OFF  = ROWFG_OFF + (size_t)NMAP * NSIDE;  // f32 [NMAP][NSIDE] (16B-aligned)

// k_bits: mask + per-row fg bitset. grid NMAP*256 blocks (one per (map,row)), 256 thr.
// Full TLP; one contiguous 32-B bitset store per block; rowFg byte; no atomics.
__global__ void k_bits(const float* __restrict__ mo, const float* __restrict__ gt,
                       u64* __restrict__ zz, unsigned char* __restrict__ rowFg) {
    int m = blockIdx.x >> 8;
    int y = blockIdx.x & 255;
    int x = threadIdx.x;
    int bit;
    if (m < NB) {   // pred: argmax over 2 channels, first-max tie -> 0
        float c0 = mo[(size_t)(m * 2 + 0) * HW + y * NSIDE + x];
        float c1 = mo[(size_t)(m * 2 + 1) * HW + y * NSIDE + x];
        bit = (c1 > c0) ? 1 : 0;
    } else {
        bit = (gt[(size_t)(m - NB) * HW + y * NSIDE + x] > 0.5f) ? 1 : 0;
    }
    u64 fg = __ballot(bit);
    __shared__ u64 s[4];
    int wid = x >> 6;
    if ((x & 63) == 0) {
        zz[((size_t)m * NSIDE + y) * 4 + wid] = fg;
        s[wid] = fg;
    }
    __syncthreads();
    if (x == 0)
        rowFg[m * NSIDE + y] = ((s[0] | s[1] | s[2] | s[3]) != 0ull) ? 1 : 0;
}

// distance from (uniform) position x to nearest SET bit of {z3:z2:z1:z0}; big if none.
// Branchless ternary chains — no runtime-indexed arrays (avoids scratch).
__device__ __forceinline__ int nbit(u64 z0, u64 z1, u64 z2, u64 z3,
                                    int xw, u64 loM, u64 hiM, int x) {
    // left: highest set bit at pos <= x
    u64 a0 = (xw == 0) ? (z0 & loM) : z0;
    u64 a1 = (xw < 1) ? 0ull : ((xw == 1) ? (z1 & loM) : z1);
    u64 a2 = (xw < 2) ? 0ull : ((xw == 2) ? (z2 & loM) : z2);
    u64 a3 = (xw < 3) ? 0ull : ((xw == 3) ? (z3 & loM) : z3);
    int msb = -(1 << 20);
    msb = a0 ? (63  - __builtin_clzll(a0)) : msb;
    msb = a1 ? (127 - __builtin_clzll(a1)) : msb;
    msb = a2 ? (191 - __builtin_clzll(a2)) : msb;
    msb = a3 ? (255 - __builtin_clzll(a3)) : msb;
    int dl = x - msb;
    // right: lowest set bit at pos >= x
    u64 b0 = (xw > 0) ? 0ull : (z0 & hiM);
    u64 b1 = (xw > 1) ? 0ull : ((xw == 1) ? (z1 & hiM) : z1);
    u64 b2 = (xw > 2) ? 0ull : ((xw == 2) ? (z2 & hiM) : z2);
    u64 b3 = (xw == 3) ? (z3 & hiM) : z3;
    int lsb = 1 << 20;
    lsb = b3 ? (192 + __builtin_ctzll(b3)) : lsb;
    lsb = b2 ? (128 + __builtin_ctzll(b2)) : lsb;
    lsb = b1 ? (64  + __builtin_ctzll(b1)) : lsb;
    lsb = b0 ? (      __builtin_ctzll(b0)) : lsb;
    int dr = lsb - x;
    return dl < dr ? dl : dr;
}

// Pass 2: row-DT from bitsets (in-register) + column DT (early-exit outward
// scan, exact vs reference brute force) + err-weighted partial sums.
// grid: NB*256 blocks (one per (image, column x)), 256 threads (one per y).
__global__ void k_colreduce(const u64* __restrict__ zz, float* __restrict__ part) {
    int b = blockIdx.x >> 8;
    int x = blockIdx.x & 255;
    int y = threadIdx.x;
    const u64* zp = &zz[((size_t)b * NSIDE + y) * 4];          // pred row y fg bits
    const u64* zg = &zz[((size_t)(NB + b) * NSIDE + y) * 4];   // gt   row y fg bits
    u64 p0 = zp[0], p1 = zp[1], p2 = zp[2], p3 = zp[3];
    u64 g0 = zg[0], g1 = zg[1], g2 = zg[2], g3 = zg[3];
    int xw = x >> 6, xb = x & 63;
    u64 loM = (2ull << xb) - 1ull;   // bits 0..xb (xb=63 wraps to all-ones)
    u64 hiM = ~0ull << xb;           // bits xb..63
    // fg-sense DT targets = zeros of fg mask = complement; bg-sense targets = fg bits
    int dPf = nbit(~p0, ~p1, ~p2, ~p3, xw, loM, hiM, x);
    int dPb = nbit( p0,  p1,  p2,  p3, xw, loM, hiM, x);
    int dGf = nbit(~g0, ~g1, ~g2, ~g3, xw, loM, hiM, x);
    int dGb = nbit( g0,  g1,  g2,  g3, xw, loM, hiM, x);
    __shared__ float cPf[NSIDE], cPb[NSIDE], cGf[NSIDE], cGb[NSIDE];
    cPf[y] = (dPf > 255) ? 1e9f : (float)(dPf * dPf);
    cPb[y] = (dPb > 255) ? 1e9f : (float)(dPb * dPb);
    cGf[y] = (dGf > 255) ? 1e9f : (float)(dGf * dGf);
    cGb[y] = (dGb > 255) ? 1e9f : (float)(dGb * dGb);
    __syncthreads();
    // err = pred bit != gt bit at (y,x); xw uniform -> scalar word select
    u64 pw = (xw == 0) ? p0 : (xw == 1) ? p1 : (xw == 2) ? p2 : p3;
    u64 gw = (xw == 0) ? g0 : (xw == 1) ? g1 : (xw == 2) ? g2 : g3;
    int predBit = (int)((pw >> xb) & 1ull);
    int gtBit   = (int)((gw >> xb) & 1ull);
    float e = (predBit != gtBit) ? 1.0f : 0.0f;
    float bPf = cPf[y], bPb = cPb[y], bGf = cGf[y], bGb = cGb[y];
    if (e == 0.0f) { bPf = 0.0f; bPb = 0.0f; bGf = 0.0f; bGb = 0.0f; }  // never hold the wave
    float fr = 0.0f;
    for (int r = 1; r < NSIDE; ++r) {
        fr += 1.0f;
        float drr = fr * fr;
        float bmax = fmaxf(fmaxf(bPf, bPb), fmaxf(bGf, bGb));   // MAX: all planes settled
        if (__all(drr >= bmax)) break;
        int jm = y - r, jp = y + r;
        int jmc = jm < 0 ? 0 : jm;
        int jpc = jp > (NSIDE - 1) ? (NSIDE - 1) : jp;
        float aPf = cPf[jmc], aPb = cPb[jmc], aGf = cGf[jmc], aGb = cGb[jmc];
        float qPf = cPf[jpc], qPb = cPb[jpc], qGf = cGf[jpc], qGb = cGb[jpc];
        if (jm < 0) { aPf = 3e9f; aPb = 3e9f; aGf = 3e9f; aGb = 3e9f; }
        if (jp > NSIDE - 1) { qPf = 3e9f; qPb = 3e9f; qGf = 3e9f; qGb = 3e9f; }
        bPf = fminf(bPf, fminf(aPf, qPf) + drr);
        bPb = fminf(bPb, fminf(aPb, qPb) + drr);
        bGf = fminf(bGf, fminf(aGf, qGf) + drr);
        bGb = fminf(bGb, fminf(aGb, qGb) + drr);
    }
    float sP = e * (bPf + bPb);   // pred_dt^2 (one sense's sqEDT is exactly 0 per pixel)
    float sG = e * (bGf + bGb);   // gt_dt^2
#pragma unroll
    for (int off = 32; off > 0; off >>= 1) {
        sP += __shfl_down(sP, off, 64);
        sG += __shfl_down(sG, off, 64);
    }
    __shared__ float rP[4], rG[4];
    int wid = threadIdx.x >> 6;
    if ((threadIdx.x & 63) == 0) { rP[wid] = sP; rG[wid] = sG; }
    __syncthreads();
    if (threadIdx.x == 0) {
        part[b * NSIDE + x]        = rP[0] + rP[1] + rP[2] + rP[3];
        part[(NB + b) * NSIDE + x] = rG[0] + rG[1] + rG[2] + rG[3];
    }
}

// Final: per-map has-fg guard + deterministic sum. 1 block, 256 threads (4 waves).
__global__ void k_final(const unsigned char* __restrict__ rowFg,
                        const float* __restrict__ part,
                        float* __restrict__ out) {
    int tid = threadIdx.x;
    int lane = tid & 63, w = tid >> 6;
    __shared__ int hasFg[NMAP];
    __shared__ float red[NMAP];
    if (tid < NMAP) hasFg[tid] = 0;
    __syncthreads();
    u64 v = ((const u64*)rowFg)[tid];     // 256 u64 = 2048 B; map = tid>>5
    if (v) atomicOr(&hasFg[tid >> 5], 1); // LDS atomic, uncontended
    // each wave reduces two maps via float4 loads
#pragma unroll
    for (int k = 0; k < 2; ++k) {
        int m = 2 * w + k;
        float4 f = ((const float4*)part)[m * 64 + lane];
        float s = f.x + f.y + f.z + f.w;
#pragma unroll
        for (int off = 32; off > 0; off >>= 1) s += __shfl_down(s, off, 64);
        if (lane == 0) red[m] = s;
    }
    __syncthreads();
    if (tid == 0) {
        double t = 0.0;
#pragma unroll
        for (int m = 0; m < NMAP; ++m)
            if (hasFg[m]) t += (double)red[m];
        out[0] = (float)(t * (1.0 / (double)(NB * HW)));
    }
}

extern "C" void kernel_launch(void* const* d_in, const int* in_sizes, int n_in,
                              void* d_out, int out_size, void* d_ws, size_t ws_size,
                              hipStream_t stream) {
    const float* mo = (const float*)d_in[0];
    const float* gt = (const float*)d_in[1];
    float* out = (float*)d_out;
    char* ws = (char*)d_ws;

    u64* zz              = (u64*)(ws + ZZ_OFF);
    unsigned char* rowFg = (unsigned char*)(ws + ROWFG_OFF);
    float* part          = (float*)(ws + PART_OFF);

    hipLaunchKernelGGL(k_bits,      dim3(NMAP * 256), dim3(256), 0, stream, mo, gt, zz, rowFg);
    hipLaunchKernelGGL(k_colreduce, dim3(NB * 256),   dim3(256), 0, stream, zz, part);
    hipLaunchKernelGGL(k_final,     dim3(1),          dim3(256), 0, stream, rowFg, part, out);
}